// Round 11
// baseline (436.458 us; speedup 1.0000x reference)
//
#include <hip/hip_runtime.h>

#define NN 100000
#define NE 400000
#define NR 3
#define DD 128
#define NROWS (NR * NN)
#define NEDGES (NR * NE)
#define SCAN_BLOCKS ((NROWS + 1023) / 1024)

typedef float f32x4 __attribute__((ext_vector_type(4)));
typedef __bf16 bf16x8 __attribute__((ext_vector_type(8)));

__device__ __forceinline__ unsigned short f2bf(float f) {
    unsigned int u = __float_as_uint(f);
    u += 0x7fff + ((u >> 16) & 1);          // round-to-nearest-even
    return (unsigned short)(u >> 16);
}
__device__ __forceinline__ float bflo(unsigned int u) { return __uint_as_float(u << 16); }
__device__ __forceinline__ float bfhi(unsigned int u) { return __uint_as_float(u & 0xffff0000u); }

__device__ __forceinline__ void gload16(const void* g, void* l) {
    __builtin_amdgcn_global_load_lds(
        (const __attribute__((address_space(1))) void*)g,
        (__attribute__((address_space(3))) void*)l, 16, 0, 0);
}

// ================= launch 1: [cvt_x | Wt2 | bias | csr_count] =================
#define NB_CVT 6250
#define NB_WT 512
#define NB_CNT 4688
__global__ __launch_bounds__(256) void prep_count(const float* __restrict__ x,
                                                  const float* __restrict__ Wn,
                                                  const float* __restrict__ Wr,
                                                  const float* __restrict__ b,
                                                  const int* __restrict__ ei,
                                                  unsigned short* __restrict__ xb,
                                                  unsigned short* __restrict__ Wt2,
                                                  float* __restrict__ bias,
                                                  int* __restrict__ cnt) {
    int bid = blockIdx.x;
    int tid = threadIdx.x;
    if (bid < NB_CVT) {
        int i = bid * 256 + tid;                       // 1.6M exact
        const float4* xf = reinterpret_cast<const float4*>(x + (size_t)i * 8);
        float4 a = xf[0], bv = xf[1];
        uint4 o;
        o.x = (unsigned)f2bf(a.x) | ((unsigned)f2bf(a.y) << 16);
        o.y = (unsigned)f2bf(a.z) | ((unsigned)f2bf(a.w) << 16);
        o.z = (unsigned)f2bf(bv.x) | ((unsigned)f2bf(bv.y) << 16);
        o.w = (unsigned)f2bf(bv.z) | ((unsigned)f2bf(bv.w) << 16);
        reinterpret_cast<uint4*>(xb)[i] = o;
    } else if (bid < NB_CVT + NB_WT) {
        int t = (bid - NB_CVT) * 256 + tid;            // 131072 exact
        int l = t >> 16;
        int rem = t & 65535;
        int n512 = rem >> 7;                            // rk*128+n
        int kk = rem & 127;
        int rk = n512 >> 7, n = n512 & 127;
        float v;
        if (rk < 3) {
            v = Wn[(((size_t)l * 3 + rk) * 128 + kk) * 128 + n];
        } else {
            const float* WrL = Wr + (size_t)l * 3 * 128 * 128;
            v = WrL[kk * 128 + n] + WrL[128 * 128 + kk * 128 + n] + WrL[2 * 128 * 128 + kk * 128 + n];
        }
        Wt2[t] = f2bf(v);                               // [l][rk*128+n][kk]
    } else if (bid == NB_CVT + NB_WT) {
        int l = tid >> 7, n = tid & 127;                // 256 = 2 layers x 128
        bias[tid] = b[l * 384 + n] + b[l * 384 + 128 + n] + b[l * 384 + 256 + n];
    } else {
        int t = (bid - NB_CVT - NB_WT - 1) * 256 + tid;
        if (t < NEDGES) {
            int r = t / NE;
            int e = t - r * NE;
            int dst = ei[(r * 2 + 1) * NE + e];
            atomicAdd(&cnt[dst * 3 + r], 1);            // rows keyed dst*3+r
        }
    }
}

// ================= scans =================
__global__ __launch_bounds__(256) void scan1(const int* __restrict__ cnt,
                                             int* __restrict__ row_start,
                                             int* __restrict__ bsum) {
    __shared__ int sh[256];
    int b0 = blockIdx.x * 1024;
    int t = threadIdx.x;
    int v[4];
    int s = 0;
    #pragma unroll
    for (int j = 0; j < 4; ++j) {
        int idx = b0 + t * 4 + j;
        v[j] = (idx < NROWS) ? cnt[idx] : 0;
        s += v[j];
    }
    sh[t] = s;
    __syncthreads();
    for (int off = 1; off < 256; off <<= 1) {
        int val = (t >= off) ? sh[t - off] : 0;
        __syncthreads();
        sh[t] += val;
        __syncthreads();
    }
    int excl = (t == 0) ? 0 : sh[t - 1];
    if (t == 255) bsum[blockIdx.x] = sh[255];
    #pragma unroll
    for (int j = 0; j < 4; ++j) {
        int idx = b0 + t * 4 + j;
        if (idx < NROWS) { row_start[idx] = excl; excl += v[j]; }
    }
}

__global__ __launch_bounds__(512) void scan2(int* __restrict__ bsum, int nb) {
    __shared__ int sh[512];
    int t = threadIdx.x;
    sh[t] = (t < nb) ? bsum[t] : 0;
    __syncthreads();
    for (int off = 1; off < 512; off <<= 1) {
        int val = (t >= off) ? sh[t - off] : 0;
        __syncthreads();
        sh[t] += val;
        __syncthreads();
    }
    int excl = (t == 0) ? 0 : sh[t - 1];
    if (t < nb) bsum[t] = excl;
}

// ================= csr_fill: 4-byte bucket entries (src<<10 | r<<8) =================
__global__ __launch_bounds__(256) void csr_fill(const int* __restrict__ ei,
                                                const int* __restrict__ row_start,
                                                const int* __restrict__ bsum,
                                                int* __restrict__ cursor,
                                                int* __restrict__ bucket) {
    int t = blockIdx.x * 256 + threadIdx.x;
    if (t >= NEDGES) return;
    int r = t / NE;
    int e = t - r * NE;
    int src = ei[(r * 2 + 0) * NE + e];
    int dst = ei[(r * 2 + 1) * NE + e];
    int i = dst * 3 + r;
    int pos = row_start[i] + bsum[i >> 10] + atomicAdd(&cursor[i], 1);
    bucket[pos] = (src << 10) | (r << 8);
}

// ================= MFMA GEMM with XCD-aware panel grouping =================
// Grid 3136 = 784 m-groups x 4 panels. Mapping puts the 4 panels of one m-group
// on the SAME XCD (dispatch round-robins bid%8): x=bid&7, j=bid>>3, p=j&3,
// m=(j>>2)*8+x  ->  panels of m sit at bids {x, x+8, x+16, x+24}.
#define NGEMM 3136
__global__ __launch_bounds__(256) void gemm_y(
    const unsigned short* __restrict__ Ab,   // [NN][128] bf16
    const unsigned short* __restrict__ WtL,  // [4][128 n][128 k] bf16, layer base
    unsigned short* __restrict__ Yb)         // [NN][512] bf16
{
    __shared__ __align__(16) unsigned short As[2 * 128 * 32];
    __shared__ __align__(16) unsigned short Bs[2 * 128 * 32];
    const int bid = blockIdx.x;
    const int x = bid & 7, j = bid >> 3;
    const int p = j & 3;
    const int mblk = (j >> 2) * 8 + x;
    const int m0 = mblk * 128;
    if (m0 >= NN) return;                    // block-uniform, before any barrier

    const int t = threadIdx.x;
    const int w = t >> 6, lane = t & 63;
    const unsigned short* WtP = WtL + p * 128 * 128;
    const int wr = w >> 1, wcol = w & 1;
    const int fr = lane & 15;
    const int fq = lane >> 4;
    const int gsw = (((lane & 3) ^ ((lane >> 2) & 3) ^ ((lane >> 4) & 3))) * 8;
    const int rsw = (fq ^ ((fr ^ (fr >> 2)) & 3)) * 8;
    f32x4 acc[4][4] = {};

    auto stage = [&](int s, int buf) {
        const int k0 = s * 32;
        #pragma unroll
        for (int i = 0; i < 2; ++i) {
            int row = i * 64 + w * 16 + (lane >> 2);
            int grow = m0 + row;
            if (grow > NN - 1) grow = NN - 1;
            const unsigned short* gA = Ab + (size_t)grow * DD + k0 + gsw;
            gload16(gA, (char*)As + buf * 8192 + i * 4096 + w * 1024);
            const unsigned short* gB = WtP + (size_t)row * 128 + k0 + gsw;
            gload16(gB, (char*)Bs + buf * 8192 + i * 4096 + w * 1024);
        }
    };

    stage(0, 0);
    #pragma unroll
    for (int s = 0; s < 4; ++s) {
        const int cur = s & 1;
        __syncthreads();
        if (s + 1 < 4) stage(s + 1, cur ^ 1);
        const unsigned short* As_c = As + cur * 4096;
        const unsigned short* Bs_c = Bs + cur * 4096;
        bf16x8 af[4], bfr[4];
        #pragma unroll
        for (int m = 0; m < 4; ++m)
            af[m] = *reinterpret_cast<const bf16x8*>(As_c + (wr * 64 + m * 16 + fr) * 32 + rsw);
        #pragma unroll
        for (int n = 0; n < 4; ++n)
            bfr[n] = *reinterpret_cast<const bf16x8*>(Bs_c + (wcol * 64 + n * 16 + fr) * 32 + rsw);
        #pragma unroll
        for (int m = 0; m < 4; ++m)
            #pragma unroll
            for (int n = 0; n < 4; ++n)
                acc[m][n] = __builtin_amdgcn_mfma_f32_16x16x32_bf16(af[m], bfr[n], acc[m][n], 0, 0, 0);
    }

    #pragma unroll
    for (int n = 0; n < 4; ++n) {
        int col = p * 128 + wcol * 64 + n * 16 + fr;
        #pragma unroll
        for (int m = 0; m < 4; ++m) {
            int rbase = m0 + wr * 64 + m * 16 + fq * 4;
            #pragma unroll
            for (int j2 = 0; j2 < 4; ++j2) {
                int row = rbase + j2;
                if (row < NN) Yb[(size_t)row * 512 + col] = f2bf(acc[m][n][j2]);
            }
        }
    }
}

// ================= fused gather: one wave per dst, 16 lanes/row x 4 rows ==============
// 4B bucket; per-edge scale reconstructed from the 3 wave-uniform degree counts.
template <int FINAL>
__global__ __launch_bounds__(256) void gather_fused(
    const unsigned short* __restrict__ Yb,
    const int* __restrict__ bucket,
    const int* __restrict__ row_start,
    const int* __restrict__ bsum,
    const int* __restrict__ cnt,
    const float* __restrict__ biasL,
    const float* __restrict__ Wc,
    const float* __restrict__ bc,
    unsigned short* __restrict__ hout,
    float* __restrict__ out)
{
    int wid = (blockIdx.x * 256 + threadIdx.x) >> 6;
    int lane = threadIdx.x & 63;
    if (wid >= NN) return;
    const int g = lane >> 4;             // edge slot within 4-group
    const int q = lane & 15;             // 16B chunk within 256B panel
    const unsigned int qoff = q * 16u;
    const char* Yc = (const char*)Yb;
    const int r3 = wid * 3;
    const int base = row_start[r3] + bsum[r3 >> 10];
    const int c0 = cnt[r3], c1 = cnt[r3 + 1], c2 = cnt[r3 + 2];
    const int degT = c0 + c1 + c2;
    const float i0 = 1.0f / (float)max(c0, 1);
    const float i1 = 1.0f / (float)max(c1, 1);
    const float i2 = 1.0f / (float)max(c2, 1);

    float acc[8] = {};
    int e = 0;
    for (; e + 8 <= degT; e += 8) {
        int ma = bucket[base + e + g];
        int mb = bucket[base + e + 4 + g];
        uint4 va = *(const uint4*)(Yc + (unsigned)ma + qoff);
        uint4 vb = *(const uint4*)(Yc + (unsigned)mb + qoff);
        int ra = (ma >> 8) & 3, rb = (mb >> 8) & 3;
        float sa = (ra == 0) ? i0 : ((ra == 1) ? i1 : i2);
        float sb = (rb == 0) ? i0 : ((rb == 1) ? i1 : i2);
        acc[0] = fmaf(bflo(va.x), sa, acc[0]); acc[1] = fmaf(bfhi(va.x), sa, acc[1]);
        acc[2] = fmaf(bflo(va.y), sa, acc[2]); acc[3] = fmaf(bfhi(va.y), sa, acc[3]);
        acc[4] = fmaf(bflo(va.z), sa, acc[4]); acc[5] = fmaf(bfhi(va.z), sa, acc[5]);
        acc[6] = fmaf(bflo(va.w), sa, acc[6]); acc[7] = fmaf(bfhi(va.w), sa, acc[7]);
        acc[0] = fmaf(bflo(vb.x), sb, acc[0]); acc[1] = fmaf(bfhi(vb.x), sb, acc[1]);
        acc[2] = fmaf(bflo(vb.y), sb, acc[2]); acc[3] = fmaf(bfhi(vb.y), sb, acc[3]);
        acc[4] = fmaf(bflo(vb.z), sb, acc[4]); acc[5] = fmaf(bfhi(vb.z), sb, acc[5]);
        acc[6] = fmaf(bflo(vb.w), sb, acc[6]); acc[7] = fmaf(bfhi(vb.w), sb, acc[7]);
    }
    for (; e < degT; e += 4) {
        if (e + g < degT) {
            int m = bucket[base + e + g];
            uint4 v = *(const uint4*)(Yc + (unsigned)m + qoff);
            int r = (m >> 8) & 3;
            float s = (r == 0) ? i0 : ((r == 1) ? i1 : i2);
            acc[0] = fmaf(bflo(v.x), s, acc[0]); acc[1] = fmaf(bfhi(v.x), s, acc[1]);
            acc[2] = fmaf(bflo(v.y), s, acc[2]); acc[3] = fmaf(bfhi(v.y), s, acc[3]);
            acc[4] = fmaf(bflo(v.z), s, acc[4]); acc[5] = fmaf(bfhi(v.z), s, acc[5]);
            acc[6] = fmaf(bflo(v.w), s, acc[6]); acc[7] = fmaf(bfhi(v.w), s, acc[7]);
        }
    }
    #pragma unroll
    for (int j = 0; j < 8; ++j) {
        acc[j] += __shfl_xor(acc[j], 16);
        acc[j] += __shfl_xor(acc[j], 32);
    }
    uint4 rv = *(const uint4*)(Yc + (size_t)wid * 1024u + 768u + qoff);
    acc[0] += bflo(rv.x); acc[1] += bfhi(rv.x);
    acc[2] += bflo(rv.y); acc[3] += bfhi(rv.y);
    acc[4] += bflo(rv.z); acc[5] += bfhi(rv.z);
    acc[6] += bflo(rv.w); acc[7] += bfhi(rv.w);
    float4 b0 = *(const float4*)(biasL + q * 8);
    float4 b1 = *(const float4*)(biasL + q * 8 + 4);
    acc[0] += b0.x; acc[1] += b0.y; acc[2] += b0.z; acc[3] += b0.w;
    acc[4] += b1.x; acc[5] += b1.y; acc[6] += b1.z; acc[7] += b1.w;

    if (!FINAL) {
        if (g == 0) {
            uint4 o;
            o.x = (unsigned)f2bf(fmaxf(acc[0], 0.f)) | ((unsigned)f2bf(fmaxf(acc[1], 0.f)) << 16);
            o.y = (unsigned)f2bf(fmaxf(acc[2], 0.f)) | ((unsigned)f2bf(fmaxf(acc[3], 0.f)) << 16);
            o.z = (unsigned)f2bf(fmaxf(acc[4], 0.f)) | ((unsigned)f2bf(fmaxf(acc[5], 0.f)) << 16);
            o.w = (unsigned)f2bf(fmaxf(acc[6], 0.f)) | ((unsigned)f2bf(fmaxf(acc[7], 0.f)) << 16);
            *reinterpret_cast<uint4*>(hout + (size_t)wid * DD + q * 8) = o;
        }
    } else {
        float4 w0 = *(const float4*)(Wc + q * 16);
        float4 w1 = *(const float4*)(Wc + q * 16 + 4);
        float4 w2 = *(const float4*)(Wc + q * 16 + 8);
        float4 w3 = *(const float4*)(Wc + q * 16 + 12);
        float p0 = acc[0] * w0.x + acc[1] * w0.z + acc[2] * w1.x + acc[3] * w1.z +
                   acc[4] * w2.x + acc[5] * w2.z + acc[6] * w3.x + acc[7] * w3.z;
        float p1 = acc[0] * w0.y + acc[1] * w0.w + acc[2] * w1.y + acc[3] * w1.w +
                   acc[4] * w2.y + acc[5] * w2.w + acc[6] * w3.y + acc[7] * w3.w;
        #pragma unroll
        for (int off = 1; off < 16; off <<= 1) {
            p0 += __shfl_xor(p0, off);
            p1 += __shfl_xor(p1, off);
        }
        if (lane == 0) {
            out[(size_t)wid * 2 + 0] = p0 + bc[0];
            out[(size_t)wid * 2 + 1] = p1 + bc[1];
        }
    }
}

extern "C" void kernel_launch(void* const* d_in, const int* in_sizes, int n_in,
                              void* d_out, int out_size, void* d_ws, size_t ws_size,
                              hipStream_t stream) {
    const float* x  = (const float*)d_in[0];
    const int*   ei = (const int*)d_in[1];
    const float* Wn = (const float*)d_in[2];
    const float* Wr = (const float*)d_in[3];
    const float* b  = (const float*)d_in[4];
    const float* Wc = (const float*)d_in[5];
    const float* bc = (const float*)d_in[6];
    float* out = (float*)d_out;

    char* p = (char*)d_ws;
    unsigned short* Yb  = (unsigned short*)p;  p += (size_t)NN * 512 * 2;        // 102.4 MB
    unsigned short* xb  = (unsigned short*)p;  p += (size_t)NN * DD * 2;         // 25.6 MB
    unsigned short* h1b = (unsigned short*)p;  p += (size_t)NN * DD * 2;         // 25.6 MB
    unsigned short* Wt2 = (unsigned short*)p;  p += (size_t)2 * 4 * 128 * 128 * 2;
    float* bias         = (float*)p;           p += 2 * 128 * 4;
    int* bucket         = (int*)p;             p += (size_t)NEDGES * 4;          // 4.8 MB
    int* row_start      = (int*)p;             p += (size_t)NROWS * 4;
    int* bsum           = (int*)p;             p += 512 * 4;
    int* cnt            = (int*)p;             p += (size_t)NROWS * 4;
    int* cursor         = (int*)p;             p += (size_t)NROWS * 4;

    hipMemsetAsync(cnt, 0, NROWS * sizeof(int), stream);
    hipMemsetAsync(cursor, 0, NROWS * sizeof(int), stream);

    // 1. [cvt_x | weights | bias | csr_count]
    prep_count<<<NB_CVT + NB_WT + 1 + NB_CNT, 256, 0, stream>>>(
        x, Wn, Wr, b, ei, xb, Wt2, bias, cnt);

    // 2-3. scans
    scan1<<<SCAN_BLOCKS, 256, 0, stream>>>(cnt, row_start, bsum);
    scan2<<<1, 512, 0, stream>>>(bsum, SCAN_BLOCKS);

    // 4. csr_fill (4B entries)
    csr_fill<<<(NEDGES + 255) / 256, 256, 0, stream>>>(ei, row_start, bsum, cursor, bucket);

    const int gatherBlocks = NN * 64 / 256;          // 25000 exact

    // 5-6. layer 0
    gemm_y<<<NGEMM, 256, 0, stream>>>(xb, Wt2, Yb);
    gather_fused<0><<<gatherBlocks, 256, 0, stream>>>(Yb, bucket, row_start, bsum, cnt,
                                                      bias, nullptr, nullptr, h1b, nullptr);

    // 7-8. layer 1 + fused classifier
    gemm_y<<<NGEMM, 256, 0, stream>>>(h1b, Wt2 + (size_t)4 * 128 * 128, Yb);
    gather_fused<1><<<gatherBlocks, 256, 0, stream>>>(Yb, bucket, row_start, bsum, cnt,
                                                      bias + 128, Wc, bc, nullptr, out);
}

// Round 12
// 434.013 us; speedup vs baseline: 1.0056x; 1.0056x over previous
//
#include <hip/hip_runtime.h>

#define NN 100000
#define NE 400000
#define NR 3
#define DD 128
#define NROWS (NR * NN)
#define NEDGES (NR * NE)
#define SCAN_BLOCKS ((NROWS + 1023) / 1024)

typedef float f32x4 __attribute__((ext_vector_type(4)));
typedef __bf16 bf16x8 __attribute__((ext_vector_type(8)));

__device__ __forceinline__ unsigned short f2bf(float f) {
    unsigned int u = __float_as_uint(f);
    u += 0x7fff + ((u >> 16) & 1);          // round-to-nearest-even
    return (unsigned short)(u >> 16);
}
__device__ __forceinline__ float bflo(unsigned int u) { return __uint_as_float(u << 16); }
__device__ __forceinline__ float bfhi(unsigned int u) { return __uint_as_float(u & 0xffff0000u); }

__device__ __forceinline__ void gload16(const void* g, void* l) {
    __builtin_amdgcn_global_load_lds(
        (const __attribute__((address_space(1))) void*)g,
        (__attribute__((address_space(3))) void*)l, 16, 0, 0);
}

// ================= launch 1: [cvt_x | Wt2 | bias | csr_count] =================
#define NB_CVT 6250
#define NB_WT 512
#define NB_CNT 4688
__global__ __launch_bounds__(256) void prep_count(const float* __restrict__ x,
                                                  const float* __restrict__ Wn,
                                                  const float* __restrict__ Wr,
                                                  const float* __restrict__ b,
                                                  const int* __restrict__ ei,
                                                  unsigned short* __restrict__ xb,
                                                  unsigned short* __restrict__ Wt2,
                                                  float* __restrict__ bias,
                                                  int* __restrict__ cnt) {
    int bid = blockIdx.x;
    int tid = threadIdx.x;
    if (bid < NB_CVT) {
        int i = bid * 256 + tid;                       // 1.6M exact
        const float4* xf = reinterpret_cast<const float4*>(x + (size_t)i * 8);
        float4 a = xf[0], bv = xf[1];
        uint4 o;
        o.x = (unsigned)f2bf(a.x) | ((unsigned)f2bf(a.y) << 16);
        o.y = (unsigned)f2bf(a.z) | ((unsigned)f2bf(a.w) << 16);
        o.z = (unsigned)f2bf(bv.x) | ((unsigned)f2bf(bv.y) << 16);
        o.w = (unsigned)f2bf(bv.z) | ((unsigned)f2bf(bv.w) << 16);
        reinterpret_cast<uint4*>(xb)[i] = o;
    } else if (bid < NB_CVT + NB_WT) {
        int t = (bid - NB_CVT) * 256 + tid;            // 131072 exact
        int l = t >> 16;
        int rem = t & 65535;
        int n512 = rem >> 7;                            // rk*128+n
        int kk = rem & 127;
        int rk = n512 >> 7, n = n512 & 127;
        float v;
        if (rk < 3) {
            v = Wn[(((size_t)l * 3 + rk) * 128 + kk) * 128 + n];
        } else {
            const float* WrL = Wr + (size_t)l * 3 * 128 * 128;
            v = WrL[kk * 128 + n] + WrL[128 * 128 + kk * 128 + n] + WrL[2 * 128 * 128 + kk * 128 + n];
        }
        Wt2[t] = f2bf(v);                               // [l][rk*128+n][kk]
    } else if (bid == NB_CVT + NB_WT) {
        int l = tid >> 7, n = tid & 127;                // 256 = 2 layers x 128
        bias[tid] = b[l * 384 + n] + b[l * 384 + 128 + n] + b[l * 384 + 256 + n];
    } else {
        int t = (bid - NB_CVT - NB_WT - 1) * 256 + tid;
        if (t < NEDGES) {
            int r = t / NE;
            int e = t - r * NE;
            int dst = ei[(r * 2 + 1) * NE + e];
            atomicAdd(&cnt[dst * 3 + r], 1);            // rows keyed dst*3+r
        }
    }
}

// ================= scans =================
__global__ __launch_bounds__(256) void scan1(const int* __restrict__ cnt,
                                             int* __restrict__ row_start,
                                             int* __restrict__ bsum) {
    __shared__ int sh[256];
    int b0 = blockIdx.x * 1024;
    int t = threadIdx.x;
    int v[4];
    int s = 0;
    #pragma unroll
    for (int j = 0; j < 4; ++j) {
        int idx = b0 + t * 4 + j;
        v[j] = (idx < NROWS) ? cnt[idx] : 0;
        s += v[j];
    }
    sh[t] = s;
    __syncthreads();
    for (int off = 1; off < 256; off <<= 1) {
        int val = (t >= off) ? sh[t - off] : 0;
        __syncthreads();
        sh[t] += val;
        __syncthreads();
    }
    int excl = (t == 0) ? 0 : sh[t - 1];
    if (t == 255) bsum[blockIdx.x] = sh[255];
    #pragma unroll
    for (int j = 0; j < 4; ++j) {
        int idx = b0 + t * 4 + j;
        if (idx < NROWS) { row_start[idx] = excl; excl += v[j]; }
    }
}

__global__ __launch_bounds__(512) void scan2(int* __restrict__ bsum, int nb) {
    __shared__ int sh[512];
    int t = threadIdx.x;
    sh[t] = (t < nb) ? bsum[t] : 0;
    __syncthreads();
    for (int off = 1; off < 512; off <<= 1) {
        int val = (t >= off) ? sh[t - off] : 0;
        __syncthreads();
        sh[t] += val;
        __syncthreads();
    }
    int excl = (t == 0) ? 0 : sh[t - 1];
    if (t < nb) bsum[t] = excl;
}

// ================= gemm body (shared by fused L0 and standalone L1) =================
// id in [0, NGEMM): x=id&7, j=id>>3, p=j&3, mblk=(j>>2)*8+x -> 4 panels of one
// m-group share an XCD (dispatch round-robins bid%8 and bid keeps x in low bits).
#define NGEMM 3136
__device__ __forceinline__ void gemm_body(int id,
                                          const unsigned short* __restrict__ Ab,
                                          const unsigned short* __restrict__ WtL,
                                          unsigned short* __restrict__ Yb,
                                          unsigned short* As, unsigned short* Bs) {
    const int x = id & 7, j = id >> 3;
    const int p = j & 3;
    const int mblk = (j >> 2) * 8 + x;
    const int m0 = mblk * 128;
    if (m0 >= NN) return;                    // block-uniform, before any barrier

    const int t = threadIdx.x;
    const int w = t >> 6, lane = t & 63;
    const unsigned short* WtP = WtL + p * 128 * 128;
    const int wr = w >> 1, wcol = w & 1;
    const int fr = lane & 15;
    const int fq = lane >> 4;
    const int gsw = (((lane & 3) ^ ((lane >> 2) & 3) ^ ((lane >> 4) & 3))) * 8;
    const int rsw = (fq ^ ((fr ^ (fr >> 2)) & 3)) * 8;
    f32x4 acc[4][4] = {};

    auto stage = [&](int s, int buf) {
        const int k0 = s * 32;
        #pragma unroll
        for (int i = 0; i < 2; ++i) {
            int row = i * 64 + w * 16 + (lane >> 2);
            int grow = m0 + row;
            if (grow > NN - 1) grow = NN - 1;
            const unsigned short* gA = Ab + (size_t)grow * DD + k0 + gsw;
            gload16(gA, (char*)As + buf * 8192 + i * 4096 + w * 1024);
            const unsigned short* gB = WtP + (size_t)row * 128 + k0 + gsw;
            gload16(gB, (char*)Bs + buf * 8192 + i * 4096 + w * 1024);
        }
    };

    stage(0, 0);
    #pragma unroll
    for (int s = 0; s < 4; ++s) {
        const int cur = s & 1;
        __syncthreads();
        if (s + 1 < 4) stage(s + 1, cur ^ 1);
        const unsigned short* As_c = As + cur * 4096;
        const unsigned short* Bs_c = Bs + cur * 4096;
        bf16x8 af[4], bfr[4];
        #pragma unroll
        for (int m = 0; m < 4; ++m)
            af[m] = *reinterpret_cast<const bf16x8*>(As_c + (wr * 64 + m * 16 + fr) * 32 + rsw);
        #pragma unroll
        for (int n = 0; n < 4; ++n)
            bfr[n] = *reinterpret_cast<const bf16x8*>(Bs_c + (wcol * 64 + n * 16 + fr) * 32 + rsw);
        #pragma unroll
        for (int m = 0; m < 4; ++m)
            #pragma unroll
            for (int n = 0; n < 4; ++n)
                acc[m][n] = __builtin_amdgcn_mfma_f32_16x16x32_bf16(af[m], bfr[n], acc[m][n], 0, 0, 0);
    }

    #pragma unroll
    for (int n = 0; n < 4; ++n) {
        int col = p * 128 + wcol * 64 + n * 16 + fr;
        #pragma unroll
        for (int m = 0; m < 4; ++m) {
            int rbase = m0 + wr * 64 + m * 16 + fq * 4;
            #pragma unroll
            for (int j2 = 0; j2 < 4; ++j2) {
                int row = rbase + j2;
                if (row < NN) Yb[(size_t)row * 512 + col] = f2bf(acc[m][n][j2]);
            }
        }
    }
}

// ================= launch 4: [gemm L0 || csr_fill], chunk-of-8 interleave ============
// Chunks of 8 blocks alternate roles so BOTH roles round-robin over all 8 XCDs.
// gemm: 392 chunks (ids keep x=bid&7 -> XCD grouping preserved); fill: 586 chunks.
#define GEMM_CHUNKS 392
#define FILL_CHUNKS 586
#define FUSE_CHUNKS (2 * GEMM_CHUNKS + (FILL_CHUNKS - GEMM_CHUNKS))   // 978
__global__ __launch_bounds__(256) void fill_gemm(
    const int* __restrict__ ei,
    const int* __restrict__ row_start,
    const int* __restrict__ bsum,
    const int* __restrict__ cnt,
    int* __restrict__ cursor,
    int2* __restrict__ bucket2,
    const unsigned short* __restrict__ Ab,
    const unsigned short* __restrict__ WtL,
    unsigned short* __restrict__ Yb)
{
    __shared__ __align__(16) unsigned short As[2 * 128 * 32];
    __shared__ __align__(16) unsigned short Bs[2 * 128 * 32];
    const int bid = blockIdx.x;
    const int c = bid >> 3, x = bid & 7;
    int role, id;
    if (c < 2 * GEMM_CHUNKS) { role = c & 1; id = (c >> 1) * 8 + x; }
    else { role = 1; id = (GEMM_CHUNKS + (c - 2 * GEMM_CHUNKS)) * 8 + x; }

    if (role == 0) {
        gemm_body(id, Ab, WtL, Yb, As, Bs);
    } else {
        int t = id * 256 + threadIdx.x;
        if (t < NEDGES) {
            int r = t / NE;
            int e = t - r * NE;
            int src = ei[(r * 2 + 0) * NE + e];
            int dst = ei[(r * 2 + 1) * NE + e];
            int i = dst * 3 + r;
            int pos = row_start[i] + bsum[i >> 10] + atomicAdd(&cursor[i], 1);
            float sc = 1.0f / (float)cnt[i];
            bucket2[pos] = make_int2((src << 10) | (r << 8), __float_as_int(sc));
        }
    }
}

// ================= standalone gemm (layer 1) =================
__global__ __launch_bounds__(256) void gemm_y(
    const unsigned short* __restrict__ Ab,
    const unsigned short* __restrict__ WtL,
    unsigned short* __restrict__ Yb)
{
    __shared__ __align__(16) unsigned short As[2 * 128 * 32];
    __shared__ __align__(16) unsigned short Bs[2 * 128 * 32];
    gemm_body(blockIdx.x, Ab, WtL, Yb, As, Bs);
}

// ================= fused gather (round-9 proven): int2 bucket, per-edge scale =========
template <int FINAL>
__global__ __launch_bounds__(256) void gather_fused(
    const unsigned short* __restrict__ Yb,
    const int2* __restrict__ bucket2,
    const int* __restrict__ row_start,
    const int* __restrict__ bsum,
    const int* __restrict__ cnt,
    const float* __restrict__ biasL,
    const float* __restrict__ Wc,
    const float* __restrict__ bc,
    unsigned short* __restrict__ hout,
    float* __restrict__ out)
{
    int wid = (blockIdx.x * 256 + threadIdx.x) >> 6;
    int lane = threadIdx.x & 63;
    if (wid >= NN) return;
    const int g = lane >> 4;             // edge slot within 4-group
    const int q = lane & 15;             // 16B chunk within 256B panel
    const unsigned int qoff = q * 16u;
    const char* Yc = (const char*)Yb;
    const int r3 = wid * 3;
    const int base = row_start[r3] + bsum[r3 >> 10];
    const int degT = cnt[r3] + cnt[r3 + 1] + cnt[r3 + 2];

    float acc[8] = {};
    int e = 0;
    for (; e + 8 <= degT; e += 8) {
        int2 ma = bucket2[base + e + g];
        int2 mb = bucket2[base + e + 4 + g];
        uint4 va = *(const uint4*)(Yc + (unsigned)ma.x + qoff);
        uint4 vb = *(const uint4*)(Yc + (unsigned)mb.x + qoff);
        float sa = __int_as_float(ma.y);
        float sb = __int_as_float(mb.y);
        acc[0] = fmaf(bflo(va.x), sa, acc[0]); acc[1] = fmaf(bfhi(va.x), sa, acc[1]);
        acc[2] = fmaf(bflo(va.y), sa, acc[2]); acc[3] = fmaf(bfhi(va.y), sa, acc[3]);
        acc[4] = fmaf(bflo(va.z), sa, acc[4]); acc[5] = fmaf(bfhi(va.z), sa, acc[5]);
        acc[6] = fmaf(bflo(va.w), sa, acc[6]); acc[7] = fmaf(bfhi(va.w), sa, acc[7]);
        acc[0] = fmaf(bflo(vb.x), sb, acc[0]); acc[1] = fmaf(bfhi(vb.x), sb, acc[1]);
        acc[2] = fmaf(bflo(vb.y), sb, acc[2]); acc[3] = fmaf(bfhi(vb.y), sb, acc[3]);
        acc[4] = fmaf(bflo(vb.z), sb, acc[4]); acc[5] = fmaf(bfhi(vb.z), sb, acc[5]);
        acc[6] = fmaf(bflo(vb.w), sb, acc[6]); acc[7] = fmaf(bfhi(vb.w), sb, acc[7]);
    }
    for (; e < degT; e += 4) {
        if (e + g < degT) {
            int2 m = bucket2[base + e + g];
            uint4 v = *(const uint4*)(Yc + (unsigned)m.x + qoff);
            float s = __int_as_float(m.y);
            acc[0] = fmaf(bflo(v.x), s, acc[0]); acc[1] = fmaf(bfhi(v.x), s, acc[1]);
            acc[2] = fmaf(bflo(v.y), s, acc[2]); acc[3] = fmaf(bfhi(v.y), s, acc[3]);
            acc[4] = fmaf(bflo(v.z), s, acc[4]); acc[5] = fmaf(bfhi(v.z), s, acc[5]);
            acc[6] = fmaf(bflo(v.w), s, acc[6]); acc[7] = fmaf(bfhi(v.w), s, acc[7]);
        }
    }
    #pragma unroll
    for (int j = 0; j < 8; ++j) {
        acc[j] += __shfl_xor(acc[j], 16);
        acc[j] += __shfl_xor(acc[j], 32);
    }
    uint4 rv = *(const uint4*)(Yc + (size_t)wid * 1024u + 768u + qoff);
    acc[0] += bflo(rv.x); acc[1] += bfhi(rv.x);
    acc[2] += bflo(rv.y); acc[3] += bfhi(rv.y);
    acc[4] += bflo(rv.z); acc[5] += bfhi(rv.z);
    acc[6] += bflo(rv.w); acc[7] += bfhi(rv.w);
    float4 b0 = *(const float4*)(biasL + q * 8);
    float4 b1 = *(const float4*)(biasL + q * 8 + 4);
    acc[0] += b0.x; acc[1] += b0.y; acc[2] += b0.z; acc[3] += b0.w;
    acc[4] += b1.x; acc[5] += b1.y; acc[6] += b1.z; acc[7] += b1.w;

    if (!FINAL) {
        if (g == 0) {
            uint4 o;
            o.x = (unsigned)f2bf(fmaxf(acc[0], 0.f)) | ((unsigned)f2bf(fmaxf(acc[1], 0.f)) << 16);
            o.y = (unsigned)f2bf(fmaxf(acc[2], 0.f)) | ((unsigned)f2bf(fmaxf(acc[3], 0.f)) << 16);
            o.z = (unsigned)f2bf(fmaxf(acc[4], 0.f)) | ((unsigned)f2bf(fmaxf(acc[5], 0.f)) << 16);
            o.w = (unsigned)f2bf(fmaxf(acc[6], 0.f)) | ((unsigned)f2bf(fmaxf(acc[7], 0.f)) << 16);
            *reinterpret_cast<uint4*>(hout + (size_t)wid * DD + q * 8) = o;
        }
    } else {
        float4 w0 = *(const float4*)(Wc + q * 16);
        float4 w1 = *(const float4*)(Wc + q * 16 + 4);
        float4 w2 = *(const float4*)(Wc + q * 16 + 8);
        float4 w3 = *(const float4*)(Wc + q * 16 + 12);
        float p0 = acc[0] * w0.x + acc[1] * w0.z + acc[2] * w1.x + acc[3] * w1.z +
                   acc[4] * w2.x + acc[5] * w2.z + acc[6] * w3.x + acc[7] * w3.z;
        float p1 = acc[0] * w0.y + acc[1] * w0.w + acc[2] * w1.y + acc[3] * w1.w +
                   acc[4] * w2.y + acc[5] * w2.w + acc[6] * w3.y + acc[7] * w3.w;
        #pragma unroll
        for (int off = 1; off < 16; off <<= 1) {
            p0 += __shfl_xor(p0, off);
            p1 += __shfl_xor(p1, off);
        }
        if (lane == 0) {
            out[(size_t)wid * 2 + 0] = p0 + bc[0];
            out[(size_t)wid * 2 + 1] = p1 + bc[1];
        }
    }
}

extern "C" void kernel_launch(void* const* d_in, const int* in_sizes, int n_in,
                              void* d_out, int out_size, void* d_ws, size_t ws_size,
                              hipStream_t stream) {
    const float* x  = (const float*)d_in[0];
    const int*   ei = (const int*)d_in[1];
    const float* Wn = (const float*)d_in[2];
    const float* Wr = (const float*)d_in[3];
    const float* b  = (const float*)d_in[4];
    const float* Wc = (const float*)d_in[5];
    const float* bc = (const float*)d_in[6];
    float* out = (float*)d_out;

    char* p = (char*)d_ws;
    unsigned short* Yb  = (unsigned short*)p;  p += (size_t)NN * 512 * 2;        // 102.4 MB
    unsigned short* xb  = (unsigned short*)p;  p += (size_t)NN * DD * 2;         // 25.6 MB
    unsigned short* h1b = (unsigned short*)p;  p += (size_t)NN * DD * 2;         // 25.6 MB
    unsigned short* Wt2 = (unsigned short*)p;  p += (size_t)2 * 4 * 128 * 128 * 2;
    float* bias         = (float*)p;           p += 2 * 128 * 4;
    int2* bucket2       = (int2*)p;            p += (size_t)NEDGES * 8;          // 9.6 MB
    int* row_start      = (int*)p;             p += (size_t)NROWS * 4;
    int* bsum           = (int*)p;             p += 512 * 4;
    int* cnt            = (int*)p;             p += (size_t)NROWS * 4;
    int* cursor         = (int*)p;             p += (size_t)NROWS * 4;

    hipMemsetAsync(cnt, 0, NROWS * sizeof(int), stream);
    hipMemsetAsync(cursor, 0, NROWS * sizeof(int), stream);

    // 1. [cvt_x | weights | bias | csr_count]
    prep_count<<<NB_CVT + NB_WT + 1 + NB_CNT, 256, 0, stream>>>(
        x, Wn, Wr, b, ei, xb, Wt2, bias, cnt);

    // 2-3. scans
    scan1<<<SCAN_BLOCKS, 256, 0, stream>>>(cnt, row_start, bsum);
    scan2<<<1, 512, 0, stream>>>(bsum, SCAN_BLOCKS);

    // 4. [gemm L0 || csr_fill] chunk-of-8 interleaved (both roles span all XCDs)
    fill_gemm<<<FUSE_CHUNKS * 8, 256, 0, stream>>>(
        ei, row_start, bsum, cnt, cursor, bucket2, xb, Wt2, Yb);

    const int gatherBlocks = NN * 64 / 256;          // 25000 exact

    // 5. gather L0
    gather_fused<0><<<gatherBlocks, 256, 0, stream>>>(Yb, bucket2, row_start, bsum, cnt,
                                                      bias, nullptr, nullptr, h1b, nullptr);

    // 6. gemm L1
    gemm_y<<<NGEMM, 256, 0, stream>>>(h1b, Wt2 + (size_t)4 * 128 * 128, Yb);

    // 7. gather L1 + fused classifier
    gather_fused<1><<<gatherBlocks, 256, 0, stream>>>(Yb, bucket2, row_start, bsum, cnt,
                                                      bias + 128, Wc, bc, nullptr, out);
}